// Round 1
// baseline (443.242 us; speedup 1.0000x reference)
//
#include <hip/hip_runtime.h>
#include <math.h>

#define BATCH 2048
#define FEAT 512
#define HIDDEN 512
#define NUM_CLASSES 1000
#define SCHUNK 8   // samples processed per W1 stream pass (registers: 2 float4 each)

__device__ __forceinline__ float fast_tanh(float x) {
    // tanh(x) = 1 - 2/(exp(2x)+1); saturates correctly for large |x|
    float e = __expf(2.0f * x);
    return 1.0f - 2.0f / (e + 1.0f);
}

__global__ __launch_bounds__(256) void disc2l_kernel(
    const float* __restrict__ Z, const int* __restrict__ y,
    const float* __restrict__ W1, const float* __restrict__ b1,
    const float* __restrict__ W2, const float* __restrict__ b2,
    float* __restrict__ out)
{
    const int c = blockIdx.x;
    const int tid = threadIdx.x;
    const int lane = tid & 63;
    const int wave = tid >> 6;

    __shared__ int s_idx[BATCH];
    __shared__ int s_count;
    __shared__ float s_part[4][SCHUNK];

    if (tid == 0) s_count = 0;
    __syncthreads();
    for (int b = tid; b < BATCH; b += 256) {
        if (y[b] == c) {
            int p = atomicAdd(&s_count, 1);
            s_idx[p] = b;
        }
    }
    __syncthreads();
    const int n = s_count;
    if (n == 0) return;

    const float4* __restrict__ W1c = (const float4*)(W1 + (size_t)c * HIDDEN * FEAT);
    const float*  __restrict__ b1c = b1 + (size_t)c * HIDDEN;
    const float*  __restrict__ W2c = W2 + (size_t)c * HIDDEN;
    const float   b2c = b2[c];

    for (int cb = 0; cb < n; cb += SCHUNK) {
        const int cn = min(SCHUNK, n - cb);

        // Preload Z fragments: lane l holds float4 #lane and #(64+lane) of each
        // sample's 512-float Z row (matching the W1 fragments it will load).
        float4 z0[SCHUNK], z1[SCHUNK];
        #pragma unroll
        for (int s = 0; s < SCHUNK; ++s) {
            if (s < cn) {
                const float4* Zs = (const float4*)(Z + (size_t)s_idx[cb + s] * FEAT);
                z0[s] = Zs[lane];
                z1[s] = Zs[64 + lane];
            } else {
                z0[s] = make_float4(0.f, 0.f, 0.f, 0.f);
                z1[s] = make_float4(0.f, 0.f, 0.f, 0.f);
            }
        }

        float oacc = 0.0f;  // lane s accumulates the output of sample cb+s

        for (int r = wave; r < HIDDEN; r += 4) {
            const float4 w0 = W1c[(size_t)r * (FEAT / 4) + lane];
            const float4 w1 = W1c[(size_t)r * (FEAT / 4) + 64 + lane];

            float aval = 0.0f;
            #pragma unroll
            for (int s = 0; s < SCHUNK; ++s) {
                if (s >= cn) break;  // wave-uniform
                float p = w0.x * z0[s].x + w0.y * z0[s].y
                        + w0.z * z0[s].z + w0.w * z0[s].w
                        + w1.x * z1[s].x + w1.y * z1[s].y
                        + w1.z * z1[s].z + w1.w * z1[s].w;
                #pragma unroll
                for (int off = 1; off < 64; off <<= 1)
                    p += __shfl_xor(p, off, 64);
                if (lane == s) aval = p;
            }
            // lanes 0..cn-1 now hold the full dot for their sample at row r
            const float t = fast_tanh(aval + b1c[r]);
            oacc += W2c[r] * t;
        }

        if (lane < cn) s_part[wave][lane] = oacc;
        __syncthreads();
        if (tid < cn) {
            float o = s_part[0][tid] + s_part[1][tid]
                    + s_part[2][tid] + s_part[3][tid] + b2c;
            out[s_idx[cb + tid]] = o;
        }
        __syncthreads();
    }
}

extern "C" void kernel_launch(void* const* d_in, const int* in_sizes, int n_in,
                              void* d_out, int out_size, void* d_ws, size_t ws_size,
                              hipStream_t stream) {
    const float* Z  = (const float*)d_in[0];
    const int*   y  = (const int*)d_in[1];
    const float* W1 = (const float*)d_in[2];
    const float* b1 = (const float*)d_in[3];
    const float* W2 = (const float*)d_in[4];
    const float* b2 = (const float*)d_in[5];
    float* out = (float*)d_out;

    disc2l_kernel<<<NUM_CLASSES, 256, 0, stream>>>(Z, y, W1, b1, W2, b2, out);
}

// Round 2
// 205.124 us; speedup vs baseline: 2.1608x; 2.1608x over previous
//
#include <hip/hip_runtime.h>
#include <math.h>

#define BATCH 2048
#define FEAT 512
#define HIDDEN 512
#define NUM_CLASSES 1000
#define SCHUNK 8
#define NTHREADS 512   // 8 waves

__device__ __forceinline__ float fast_tanh(float x) {
    // tanh(x) = 1 - 2/(exp(2x)+1); saturates correctly for large |x|
    float e = __expf(2.0f * x);
    return 1.0f - 2.0f / (e + 1.0f);
}

__global__ __launch_bounds__(NTHREADS) void disc2l_kernel(
    const float* __restrict__ Z, const int* __restrict__ y,
    const float* __restrict__ W1, const float* __restrict__ b1,
    const float* __restrict__ W2, const float* __restrict__ b2,
    float* __restrict__ out)
{
    const int c = blockIdx.x;
    const int tid = threadIdx.x;
    const int lane = tid & 63;
    const int wave = tid >> 6;      // 0..7
    const int q = lane >> 4;        // 16-lane cluster 0..3 (row within group)
    const int ms = lane & 15;       // position within cluster

    __shared__ int s_idx[BATCH];        // 8 KB
    __shared__ int s_count;
    __shared__ float s_z[SCHUNK][FEAT]; // 16 KB
    __shared__ float s_b1[HIDDEN];      // 2 KB
    __shared__ float s_w2[HIDDEN];      // 2 KB
    __shared__ float s_part[8][SCHUNK];

    if (tid == 0) s_count = 0;
    __syncthreads();
    for (int b = tid; b < BATCH; b += NTHREADS) {
        if (y[b] == c) {
            int p = atomicAdd(&s_count, 1);
            s_idx[p] = b;
        }
    }
    __syncthreads();
    const int n = s_count;
    if (n == 0) return;

    // stage b1, W2 for this class (one float4 instruction each region)
    {
        const float4* b1v = (const float4*)(b1 + (size_t)c * HIDDEN);
        const float4* w2v = (const float4*)(W2 + (size_t)c * HIDDEN);
        if (tid < 128) ((float4*)s_b1)[tid] = b1v[tid];
        else if (tid < 256) ((float4*)s_w2)[tid - 128] = w2v[tid - 128];
    }
    const float* W1c = W1 + (size_t)c * HIDDEN * FEAT;
    const float b2c = b2[c];

    for (int cb = 0; cb < n; cb += SCHUNK) {
        const int cn = min(SCHUNK, n - cb);

        // stage Z rows for this chunk: 128 threads per sample, 4 samples/round
        __syncthreads();   // previous chunk's s_z reads (and b1/w2 stage) done
        #pragma unroll
        for (int s0 = 0; s0 < SCHUNK; s0 += 4) {
            const int s = s0 + (tid >> 7);
            if (s < cn) {
                const float4* Zs = (const float4*)(Z + (size_t)s_idx[cb + s] * FEAT);
                ((float4*)s_z[s])[tid & 127] = Zs[tid & 127];
            }
        }
        __syncthreads();

        float oacc = 0.0f;   // lane (q, ms): partial output of sample ms over rows = q (mod 4)

        // 128 groups of 4 rows; wave w handles groups w, w+8, ...
        for (int g = wave; g < HIDDEN / 4; g += 8) {
            const int row = 4 * g + q;
            const float4* Wrow = (const float4*)(W1c + (size_t)row * FEAT);

            // 8 independent 16B loads, all in flight before first use
            float4 wv[8];
            #pragma unroll
            for (int k = 0; k < 8; ++k)
                wv[k] = Wrow[k * 16 + ms];

            float part[SCHUNK];
            #pragma unroll
            for (int s = 0; s < SCHUNK; ++s) part[s] = 0.0f;

            #pragma unroll
            for (int k = 0; k < 8; ++k) {
                #pragma unroll
                for (int s = 0; s < SCHUNK; ++s) {
                    if (s < cn) {   // wave-uniform guard
                        const float4 zv = ((const float4*)(&s_z[s][k * 64]))[ms];
                        part[s] += wv[k].x * zv.x + wv[k].y * zv.y
                                 + wv[k].z * zv.z + wv[k].w * zv.w;
                    }
                }
            }

            // reduce each sample's partial across the 16-lane cluster
            #pragma unroll
            for (int s = 0; s < SCHUNK; ++s) {
                if (s < cn) {
                    part[s] += __shfl_xor(part[s], 1, 64);
                    part[s] += __shfl_xor(part[s], 2, 64);
                    part[s] += __shfl_xor(part[s], 4, 64);
                    part[s] += __shfl_xor(part[s], 8, 64);
                }
            }

            // lane (q, ms): take sample ms's full dot for this cluster's row
            if (ms < cn) {
                float v = part[0];
                #pragma unroll
                for (int s = 1; s < SCHUNK; ++s)
                    if (ms == s) v = part[s];
                const float t = fast_tanh(v + s_b1[row]);
                oacc += s_w2[row] * t;
            }
        }

        // combine the 4 clusters (rows mod 4), then the 8 waves
        oacc += __shfl_xor(oacc, 16, 64);
        oacc += __shfl_xor(oacc, 32, 64);
        if (lane < cn) s_part[wave][lane] = oacc;   // lane<16 has q-reduced value
        __syncthreads();
        if (tid < cn) {
            float o = b2c;
            #pragma unroll
            for (int w = 0; w < 8; ++w) o += s_part[w][tid];
            out[s_idx[cb + tid]] = o;
        }
    }
}

extern "C" void kernel_launch(void* const* d_in, const int* in_sizes, int n_in,
                              void* d_out, int out_size, void* d_ws, size_t ws_size,
                              hipStream_t stream) {
    const float* Z  = (const float*)d_in[0];
    const int*   y  = (const int*)d_in[1];
    const float* W1 = (const float*)d_in[2];
    const float* b1 = (const float*)d_in[3];
    const float* W2 = (const float*)d_in[4];
    const float* b2 = (const float*)d_in[5];
    float* out = (float*)d_out;

    disc2l_kernel<<<NUM_CLASSES, NTHREADS, 0, stream>>>(Z, y, W1, b1, W2, b2, out);
}